// Round 1
// baseline (259.969 us; speedup 1.0000x reference)
//
#include <hip/hip_runtime.h>

// Problem constants (fixed by the reference)
constexpr int C_ = 2048;
constexpr int H_ = 16;
constexpr int W_ = 16;
constexpr int F_ = 64;
constexpr int P_ = 256;              // samples per complex

// One block per complex, 256 threads.
// Phase 1 (cheap): each thread computes bilinear coeffs for one sample,
//                  stores pre-combined weights (float4) + texel index to 5 KB LDS.
// Phase 2: 16 threads per sample (float4 over F), 16 samples/iter, 16 iters.
//          Texels gathered DIRECTLY from global: map[c] is 64 KB and stays hot
//          in L2/L3 (whole map tensor = 128 MB < 256 MB L3). No 64 KB LDS stage
//          -> occupancy rises from 2 blocks/CU to the grid cap of 8 blocks/CU.
__global__ __launch_bounds__(256) void ngf_fetch_kernel(
    const float* __restrict__ map_,
    const float* __restrict__ u_,
    const float* __restrict__ v_,
    float* __restrict__ out_) {
  __shared__ float4 s_w[P_];      // (w00, w01, w10, w11) per sample
  __shared__ int    s_ix[P_];     // (y0*W + x0) * (F/4), in float4 units

  const int c = blockIdx.x;
  const int tid = threadIdx.x;

  // ---- per-sample coefficients (one sample per thread) ----
  {
    const float x = u_[(size_t)c * P_ + tid] * (float)(W_ - 1);
    const float y = v_[(size_t)c * P_ + tid] * (float)(H_ - 1);
    int x0 = (int)floorf(x);
    int y0 = (int)floorf(y);
    x0 = x0 < 0 ? 0 : (x0 > W_ - 2 ? W_ - 2 : x0);
    y0 = y0 < 0 ? 0 : (y0 > H_ - 2 ? H_ - 2 : y0);
    const float fx = x - (float)x0;
    const float fy = y - (float)y0;
    const float wx0 = 1.0f - fx;
    const float wy0 = 1.0f - fy;
    s_w[tid] = make_float4(wx0 * wy0, fx * wy0, wx0 * fy, fx * fy);
    s_ix[tid] = (y0 * W_ + x0) * (F_ / 4);
  }
  __syncthreads();

  // ---- gather (from global, L2/L3-served) + weighted sum + store ----
  const float4* __restrict__ gmap =
      (const float4*)(map_ + (size_t)c * (H_ * W_ * F_));
  float4* __restrict__ gout = (float4*)(out_ + (size_t)c * (P_ * F_));
  const int f = tid & 15;        // float4 index along feature dim (0..15)
  const int sbase = tid >> 4;    // 0..15

#pragma unroll
  for (int it = 0; it < 16; ++it) {
    const int s = it * 16 + sbase;           // wave's 4 samples are consecutive
    const float4 w = s_w[s];                 // LDS broadcast (16 lanes same addr)
    const int ix = s_ix[s] + f;

    const float4 g00 = gmap[ix];
    const float4 g01 = gmap[ix + (F_ / 4)];            // x0+1
    const float4 g10 = gmap[ix + W_ * (F_ / 4)];       // y0+1
    const float4 g11 = gmap[ix + (W_ + 1) * (F_ / 4)]; // y0+1, x0+1

    float4 r;
    r.x = g00.x * w.x + g01.x * w.y + g10.x * w.z + g11.x * w.w;
    r.y = g00.y * w.x + g01.y * w.y + g10.y * w.z + g11.y * w.w;
    r.z = g00.z * w.x + g01.z * w.y + g10.z * w.z + g11.z * w.w;
    r.w = g00.w * w.x + g01.w * w.y + g10.w * w.z + g11.w * w.w;

    gout[s * (F_ / 4) + f] = r;   // wave writes 1 KB contiguous
  }
}

extern "C" void kernel_launch(void* const* d_in, const int* in_sizes, int n_in,
                              void* d_out, int out_size, void* d_ws, size_t ws_size,
                              hipStream_t stream) {
  const float* map_ = (const float*)d_in[0];
  const float* u_   = (const float*)d_in[1];
  const float* v_   = (const float*)d_in[2];
  float* out_ = (float*)d_out;

  ngf_fetch_kernel<<<C_, 256, 0, stream>>>(map_, u_, v_, out_);
}

// Round 2
// 237.020 us; speedup vs baseline: 1.0968x; 1.0968x over previous
//
#include <hip/hip_runtime.h>

// Problem constants (fixed by the reference)
constexpr int C_ = 2048;
constexpr int H_ = 16;
constexpr int W_ = 16;
constexpr int F_ = 64;
constexpr int P_ = 256;                 // samples per complex
constexpr int MAP4 = H_ * W_ * F_ / 4;  // 4096 float4 = 64 KB
constexpr int BLK = 1024;               // 16 waves per block

// One block per complex, 1024 threads (16 waves).
// Round-1 lesson: direct-global gather doubles HBM fetch (145 MB vs 67 MB) --
// the LDS stage converts 256 KB/complex of random texel reads into one 64 KB
// streaming read. Keep the stage; fix the occupancy tax instead:
// 69 KB LDS at 256 threads = 2 blocks/CU = 8 waves (17% occ, the old limiter).
// Same LDS at 1024 threads = 2 blocks/CU = 32 waves (100% cap).
// __launch_bounds__(1024, 8): 8 waves/EU min -> 2 blocks/CU -> VGPR <= 64.
__global__ __launch_bounds__(BLK, 8) void ngf_fetch_kernel(
    const float* __restrict__ map_,
    const float* __restrict__ u_,
    const float* __restrict__ v_,
    float* __restrict__ out_) {
  __shared__ float4 smap[MAP4];   // 64 KB: map[c] as [H][W][F/4] float4
  __shared__ float4 s_w[P_];      // (w00, w01, w10, w11) per sample
  __shared__ int    s_ix[P_];     // (y0*W + x0) * (F/4), in float4 units

  const int c = blockIdx.x;
  const int tid = threadIdx.x;

  // ---- stage map tile: 4096 float4 / 1024 threads = 4 each, coalesced ----
  const float4* __restrict__ gmap =
      (const float4*)(map_ + (size_t)c * (H_ * W_ * F_));
#pragma unroll
  for (int i = 0; i < MAP4 / BLK; ++i) {
    smap[i * BLK + tid] = gmap[i * BLK + tid];
  }

  // ---- per-sample coefficients (first 4 waves; one sample per thread) ----
  if (tid < P_) {
    const float x = u_[(size_t)c * P_ + tid] * (float)(W_ - 1);
    const float y = v_[(size_t)c * P_ + tid] * (float)(H_ - 1);
    int x0 = (int)floorf(x);
    int y0 = (int)floorf(y);
    x0 = x0 < 0 ? 0 : (x0 > W_ - 2 ? W_ - 2 : x0);
    y0 = y0 < 0 ? 0 : (y0 > H_ - 2 ? H_ - 2 : y0);
    const float fx = x - (float)x0;
    const float fy = y - (float)y0;
    const float wx0 = 1.0f - fx;
    const float wy0 = 1.0f - fy;
    s_w[tid] = make_float4(wx0 * wy0, fx * wy0, wx0 * fy, fx * fy);
    s_ix[tid] = (y0 * W_ + x0) * (F_ / 4);
  }
  __syncthreads();

  // ---- gather from LDS + weighted sum + store ----
  float4* __restrict__ gout = (float4*)(out_ + (size_t)c * (P_ * F_));
  const int f = tid & 15;        // float4 index along feature dim (0..15)
  const int sbase = tid >> 4;    // 0..63

#pragma unroll
  for (int it = 0; it < P_ / (BLK / 16); ++it) {  // 4 iterations
    const int s = it * (BLK / 16) + sbase;        // sample index
    const float4 w = s_w[s];                      // LDS broadcast
    const int ix = s_ix[s] + f;

    const float4 g00 = smap[ix];
    const float4 g01 = smap[ix + (F_ / 4)];            // x0+1
    const float4 g10 = smap[ix + W_ * (F_ / 4)];       // y0+1
    const float4 g11 = smap[ix + (W_ + 1) * (F_ / 4)]; // y0+1, x0+1

    float4 r;
    r.x = g00.x * w.x + g01.x * w.y + g10.x * w.z + g11.x * w.w;
    r.y = g00.y * w.x + g01.y * w.y + g10.y * w.z + g11.y * w.w;
    r.z = g00.z * w.x + g01.z * w.y + g10.z * w.z + g11.z * w.w;
    r.w = g00.w * w.x + g01.w * w.y + g10.w * w.z + g11.w * w.w;

    gout[s * (F_ / 4) + f] = r;   // wave writes 1 KB contiguous
  }
}

extern "C" void kernel_launch(void* const* d_in, const int* in_sizes, int n_in,
                              void* d_out, int out_size, void* d_ws, size_t ws_size,
                              hipStream_t stream) {
  const float* map_ = (const float*)d_in[0];
  const float* u_   = (const float*)d_in[1];
  const float* v_   = (const float*)d_in[2];
  float* out_ = (float*)d_out;

  ngf_fetch_kernel<<<C_, BLK, 0, stream>>>(map_, u_, v_, out_);
}